// Round 2
// baseline (154.606 us; speedup 1.0000x reference)
//
#include <hip/hip_runtime.h>
#include <hip/hip_bf16.h>
#include <cstdint>

typedef __attribute__((ext_vector_type(4))) int i32x4;

#define XROWS 22
#define XW    22
#define XCI   80                 // 64 data + 16 pad bytes; multiple of 16 (b128 align), banks uniform
#define XROWB (XW * XCI)         // 1760 B
#define WSLICE 8192

__device__ __forceinline__ void g2lds16(const void* g, void* l) {
  __builtin_amdgcn_global_load_lds(
      (const __attribute__((address_space(1))) unsigned int*)g,
      (__attribute__((address_space(3))) unsigned int*)l, 16, 0, 0);
}

// Pack W7 (reconstructed from w1/w2/w3) into int8, layout per 7x7 slice s=kh*7+kw:
//   wb[((s*4 + g)*128 + co)*16 + lo]  with ci = g*16 + lo
__global__ void prep_w(const float* __restrict__ w1,
                       const float* __restrict__ w2,
                       const float* __restrict__ w3,
                       signed char* __restrict__ wb) {
  int t = blockIdx.x * 256 + threadIdx.x;
  int lo = t & 15;
  int co = (t >> 4) & 127;
  int g  = (t >> 11) & 3;
  int s  = t >> 13;
  if (s >= 49) return;
  int kh = s / 7, kw = s % 7;
  int ci = g * 16 + lo;
  int base = ((co * 64 + ci) * 7 + kh) * 3;
  float v;
  if (kw < 3)       v = w1[base + kw];
  else if (kw == 3) v = w2[base + 1];
  else              v = w3[base + kw - 4];
  wb[t] = (signed char)(int)v;
}

__global__ __launch_bounds__(256, 2)
void conv7(const int* __restrict__ x,
           const signed char* __restrict__ wb,
           float* __restrict__ out) {
  __shared__ __align__(16) unsigned char Xs[XROWS * XROWB]; // 38720 B
  __shared__ __align__(16) unsigned char Ws[2][WSLICE];     // 16384 B

  const int tid  = threadIdx.x;
  const int lane = tid & 63;
  const int wid  = tid >> 6;
  const int lrow = lane & 15;
  const int lkg  = lane >> 4;
  const int n       = blockIdx.z;
  const int ho_base = blockIdx.y * 16;
  const int wo_base = blockIdx.x * 16;

  // ---- stage X: [r][w][ci] int8, dword-packed writes (4 ci per write) — bank-conflict-free
  {
    const int w1p = tid & 15, cg1 = tid >> 4;          // slots 0..255
    const int w2p = 16 + tid % 6, cg2 = tid / 6;       // slots 256..351 (tid<96)
    for (int r = 0; r < XROWS; ++r) {
      int h = ho_base + r; h = h < 112 ? h : 111;      // clamped rows feed only masked outputs
      {
        int wc = wo_base + w1p; wc = wc < 112 ? wc : 111;
        const int* p = x + (size_t)(n * 64 + cg1 * 4) * 12544 + h * 112 + wc;
        int a0 = p[0], a1 = p[12544], a2 = p[25088], a3 = p[37632];
        a0 = a0 < 0 ? 0 : (a0 > 7 ? 7 : a0);
        a1 = a1 < 0 ? 0 : (a1 > 7 ? 7 : a1);
        a2 = a2 < 0 ? 0 : (a2 > 7 ? 7 : a2);
        a3 = a3 < 0 ? 0 : (a3 > 7 ? 7 : a3);
        uint32_t v = (uint32_t)a0 | ((uint32_t)a1 << 8) | ((uint32_t)a2 << 16) | ((uint32_t)a3 << 24);
        *(uint32_t*)&Xs[r * XROWB + w1p * XCI + cg1 * 4] = v;
      }
      if (tid < 96) {
        int wc = wo_base + w2p; wc = wc < 112 ? wc : 111;
        const int* p = x + (size_t)(n * 64 + cg2 * 4) * 12544 + h * 112 + wc;
        int a0 = p[0], a1 = p[12544], a2 = p[25088], a3 = p[37632];
        a0 = a0 < 0 ? 0 : (a0 > 7 ? 7 : a0);
        a1 = a1 < 0 ? 0 : (a1 > 7 ? 7 : a1);
        a2 = a2 < 0 ? 0 : (a2 > 7 ? 7 : a2);
        a3 = a3 < 0 ? 0 : (a3 > 7 ? 7 : a3);
        uint32_t v = (uint32_t)a0 | ((uint32_t)a1 << 8) | ((uint32_t)a2 << 16) | ((uint32_t)a3 << 24);
        *(uint32_t*)&Xs[r * XROWB + w2p * XCI + cg2 * 4] = v;
      }
    }
    // issue W slice 0 (drained by the __syncthreads below)
    g2lds16(wb + (wid * 2 + 0) * 1024 + lane * 16, &Ws[0][(wid * 2 + 0) * 1024 + lane * 16]);
    g2lds16(wb + (wid * 2 + 1) * 1024 + lane * 16, &Ws[0][(wid * 2 + 1) * 1024 + lane * 16]);
  }
  __syncthreads();

  const int co_half = wid >> 1;                        // waves: [2 co][2 spatial]
  const int sp_half = wid & 1;
  const int aBase = lkg * 2048 + co_half * 1024 + lrow * 16;
  const int bBase = (sp_half * 8) * XROWB + lrow * XCI + lkg * 16;

  i32x4 acc[4][8];
  #pragma unroll
  for (int m = 0; m < 4; ++m)
    #pragma unroll
    for (int b = 0; b < 8; ++b)
      acc[m][b] = (i32x4){0, 0, 0, 0};

  int s = 0;
  for (int kh = 0; kh < 7; ++kh) {
    #pragma unroll
    for (int kw = 0; kw < 7; ++kw, ++s) {
      // own W(s) chunks complete; then all-waves barrier => full slice s resident
      asm volatile("s_waitcnt vmcnt(0)" ::: "memory");
      __builtin_amdgcn_s_barrier();
      asm volatile("" ::: "memory");                   // no LDS reads hoist above the barrier
      __builtin_amdgcn_sched_barrier(0);
      // depth-1 prefetch of W(s+1); stays in flight across this slice's MFMAs
      if (s < 48) {
        const signed char* nxt = wb + (s + 1) * WSLICE;
        unsigned char* dst = &Ws[(s + 1) & 1][0];
        g2lds16(nxt + (wid * 2 + 0) * 1024 + lane * 16, dst + (wid * 2 + 0) * 1024 + lane * 16);
        g2lds16(nxt + (wid * 2 + 1) * 1024 + lane * 16, dst + (wid * 2 + 1) * 1024 + lane * 16);
      }
      const unsigned char* wbuf = &Ws[s & 1][0];
      i32x4 A[4], B[8];
      #pragma unroll
      for (int m = 0; m < 4; ++m)
        A[m] = *(const i32x4*)(wbuf + aBase + m * 256);
      #pragma unroll
      for (int b = 0; b < 8; ++b)
        B[b] = *(const i32x4*)(&Xs[(b + kh) * XROWB + kw * XCI + bBase]);
      #pragma unroll
      for (int m = 0; m < 4; ++m)
        #pragma unroll
        for (int b = 0; b < 8; ++b)
          acc[m][b] = __builtin_amdgcn_mfma_i32_16x16x64_i8(A[m], B[b], acc[m][b], 0, 0, 0);
    }
  }

  // ---- epilogue: C/D map col=lane&15 (wo), row=(lane>>4)*4+j (co); i32 -> f32 exact
  const int wo = wo_base + lrow;
  if (wo < 106) {
    #pragma unroll
    for (int m = 0; m < 4; ++m) {
      const int co = co_half * 64 + m * 16 + lkg * 4;
      #pragma unroll
      for (int b = 0; b < 8; ++b) {
        const int ho = ho_base + sp_half * 8 + b;
        if (ho < 106) {
          float* op = out + (((size_t)n * 128 + co) * 106 + ho) * 106 + wo;
          #pragma unroll
          for (int j = 0; j < 4; ++j)
            op[(size_t)j * 11236] = (float)acc[m][b][j];
        }
      }
    }
  }
}

extern "C" void kernel_launch(void* const* d_in, const int* in_sizes, int n_in,
                              void* d_out, int out_size, void* d_ws, size_t ws_size,
                              hipStream_t stream) {
  const int*   x  = (const int*)d_in[0];
  const float* w1 = (const float*)d_in[1];
  const float* w2 = (const float*)d_in[2];
  const float* w3 = (const float*)d_in[3];
  float* outp = (float*)d_out;
  signed char* wbp = (signed char*)d_ws;   // 49*8192 = 401408 B of scratch

  prep_w<<<dim3(1568), dim3(256), 0, stream>>>(w1, w2, w3, wbp);
  conv7<<<dim3(7, 7, 16), dim3(256), 0, stream>>>(x, wbp, outp);
}

// Round 3
// 131.436 us; speedup vs baseline: 1.1763x; 1.1763x over previous
//
#include <hip/hip_runtime.h>
#include <cstdint>

typedef __attribute__((ext_vector_type(4))) int i32x4;

#define XW    22
#define XROWS 22
#define XROWB (XW * 64)          // 1408 B per row
#define WSLICE 8192

// Pack W7 (reconstructed from w1/w2/w3) into int8, layout per 7x7 slice s=kh*7+kw:
//   wb[((s*4 + g)*128 + co)*16 + lo]  with ci = g*16 + lo
__global__ void prep_w(const float* __restrict__ w1,
                       const float* __restrict__ w2,
                       const float* __restrict__ w3,
                       signed char* __restrict__ wb) {
  int t = blockIdx.x * 256 + threadIdx.x;
  int lo = t & 15;
  int co = (t >> 4) & 127;
  int g  = (t >> 11) & 3;
  int s  = t >> 13;
  if (s >= 49) return;
  int kh = s / 7, kw = s % 7;
  int ci = g * 16 + lo;
  int base = ((co * 64 + ci) * 7 + kh) * 3;
  float v;
  if (kw < 3)       v = w1[base + kw];
  else if (kw == 3) v = w2[base + 1];
  else              v = w3[base + kw - 4];
  wb[t] = (signed char)(int)v;
}

__global__ __launch_bounds__(256, 2)
void conv7(const int* __restrict__ x,
           const signed char* __restrict__ wb,
           float* __restrict__ out) {
  __shared__ __align__(16) unsigned char Xs[XROWS * XROWB];   // 30976 B

  const int tid  = threadIdx.x;
  const int lane = tid & 63;
  const int wid  = tid >> 6;
  const int lrow = lane & 15;
  const int lkg  = lane >> 4;
  const int n       = blockIdx.z;
  const int ho_base = blockIdx.y * 16;
  const int wo_base = blockIdx.x * 16;

  // ---- stage X: [r][w][cg^key] dwords (4 ci per dword), swizzled so both the
  // dword writes (2/bank) and the b128 reads (8 lanes -> 8 distinct quads) are clean.
  {
    const int w_a  = tid & 15;            // w 0..15, lane-fast => coalesced
    const int cg_a = tid >> 4;            // ci-group 0..15
    const int w_b  = 16 + (tid & 7);      // w 16..21 (mask (tid&7)<6)
    const int cg_b = tid >> 3;            // 0..15 for tid<128
    const bool doB = (tid < 128) && ((tid & 7) < 6);
    const int keyA = ((w_a >> 1) & 3) << 2;
    const int keyB = ((w_b >> 1) & 3) << 2;
    for (int r = 0; r < XROWS; ++r) {
      int h = ho_base + r; h = h < 112 ? h : 111;       // clamped rows feed only masked outputs
      const int* xr = x + (size_t)n * 64 * 12544 + h * 112;
      {
        int wc = wo_base + w_a; wc = wc < 112 ? wc : 111;
        uint32_t v = 0;
        #pragma unroll
        for (int j = 0; j < 4; ++j) {
          int a = xr[(cg_a * 4 + j) * 12544 + wc];
          a = a < 0 ? 0 : (a > 7 ? 7 : a);
          v |= (uint32_t)a << (8 * j);
        }
        *(uint32_t*)&Xs[r * XROWB + w_a * 64 + ((cg_a ^ keyA) << 2)] = v;
      }
      if (doB) {
        int wc = wo_base + w_b; wc = wc < 112 ? wc : 111;
        uint32_t v = 0;
        #pragma unroll
        for (int j = 0; j < 4; ++j) {
          int a = xr[(cg_b * 4 + j) * 12544 + wc];
          a = a < 0 ? 0 : (a > 7 ? 7 : a);
          v |= (uint32_t)a << (8 * j);
        }
        *(uint32_t*)&Xs[r * XROWB + w_b * 64 + ((cg_b ^ keyB) << 2)] = v;
      }
    }
  }

  const int co_half = wid >> 1;                     // waves: [2 co][2 spatial]
  const int sp_half = wid & 1;
  // A-frags come straight from global (L2-hot): no LDS, no barriers.
  const signed char* aB = wb + lkg * 2048 + co_half * 1024 + lrow * 16;

  i32x4 Aa[4], Ab[4];
  #pragma unroll
  for (int m = 0; m < 4; ++m)
    Aa[m] = *(const i32x4*)(aB + m * 256);          // slice 0

  __syncthreads();                                   // the only barrier: Xs ready

  i32x4 acc[4][8];
  #pragma unroll
  for (int m = 0; m < 4; ++m)
    #pragma unroll
    for (int b = 0; b < 8; ++b)
      acc[m][b] = (i32x4){0, 0, 0, 0};

  const int rowB = sp_half * 8;
  int kh = 0, kw = 0;
  for (int s = 0; s < 48; s += 2) {
    {   // even slice s: compute with Aa, prefetch s+1 -> Ab
      const signed char* ap = aB + (s + 1) * WSLICE;
      #pragma unroll
      for (int m = 0; m < 4; ++m) Ab[m] = *(const i32x4*)(ap + m * 256);
      const int w = lrow + kw;
      const int bb = (rowB + kh) * XROWB + w * 64 + ((lkg ^ ((w >> 1) & 3)) << 4);
      i32x4 B[8];
      #pragma unroll
      for (int b = 0; b < 8; ++b) B[b] = *(const i32x4*)&Xs[bb + b * XROWB];
      #pragma unroll
      for (int m = 0; m < 4; ++m)
        #pragma unroll
        for (int b = 0; b < 8; ++b)
          acc[m][b] = __builtin_amdgcn_mfma_i32_16x16x64_i8(Aa[m], B[b], acc[m][b], 0, 0, 0);
      ++kw; if (kw == 7) { kw = 0; ++kh; }
    }
    {   // odd slice s+1: compute with Ab, prefetch s+2 -> Aa
      const signed char* ap = aB + (s + 2) * WSLICE;
      #pragma unroll
      for (int m = 0; m < 4; ++m) Aa[m] = *(const i32x4*)(ap + m * 256);
      const int w = lrow + kw;
      const int bb = (rowB + kh) * XROWB + w * 64 + ((lkg ^ ((w >> 1) & 3)) << 4);
      i32x4 B[8];
      #pragma unroll
      for (int b = 0; b < 8; ++b) B[b] = *(const i32x4*)&Xs[bb + b * XROWB];
      #pragma unroll
      for (int m = 0; m < 4; ++m)
        #pragma unroll
        for (int b = 0; b < 8; ++b)
          acc[m][b] = __builtin_amdgcn_mfma_i32_16x16x64_i8(Ab[m], B[b], acc[m][b], 0, 0, 0);
      ++kw; if (kw == 7) { kw = 0; ++kh; }
    }
  }
  {   // slice 48 (kh=6, kw=6), Aa holds it
    const int w = lrow + 6;
    const int bb = (rowB + 6) * XROWB + w * 64 + ((lkg ^ ((w >> 1) & 3)) << 4);
    i32x4 B[8];
    #pragma unroll
    for (int b = 0; b < 8; ++b) B[b] = *(const i32x4*)&Xs[bb + b * XROWB];
    #pragma unroll
    for (int m = 0; m < 4; ++m)
      #pragma unroll
      for (int b = 0; b < 8; ++b)
        acc[m][b] = __builtin_amdgcn_mfma_i32_16x16x64_i8(Aa[m], B[b], acc[m][b], 0, 0, 0);
  }

  // ---- epilogue: C/D map col=lane&15 (wo), row=(lane>>4)*4+j (co); i32 -> f32 exact
  const int wo = wo_base + lrow;
  if (wo < 106) {
    #pragma unroll
    for (int m = 0; m < 4; ++m) {
      const int co = co_half * 64 + m * 16 + lkg * 4;
      #pragma unroll
      for (int b = 0; b < 8; ++b) {
        const int ho = ho_base + sp_half * 8 + b;
        if (ho < 106) {
          float* op = out + (((size_t)n * 128 + co) * 106 + ho) * 106 + wo;
          #pragma unroll
          for (int j = 0; j < 4; ++j)
            op[(size_t)j * 11236] = (float)acc[m][b][j];
        }
      }
    }
  }
}

extern "C" void kernel_launch(void* const* d_in, const int* in_sizes, int n_in,
                              void* d_out, int out_size, void* d_ws, size_t ws_size,
                              hipStream_t stream) {
  const int*   x  = (const int*)d_in[0];
  const float* w1 = (const float*)d_in[1];
  const float* w2 = (const float*)d_in[2];
  const float* w3 = (const float*)d_in[3];
  float* outp = (float*)d_out;
  signed char* wbp = (signed char*)d_ws;   // 49*8192 = 401408 B of scratch

  prep_w<<<dim3(1568), dim3(256), 0, stream>>>(w1, w2, w3, wbp);
  conv7<<<dim3(7, 7, 16), dim3(256), 0, stream>>>(x, wbp, outp);
}

// Round 4
// 86.105 us; speedup vs baseline: 1.7955x; 1.5265x over previous
//
#include <hip/hip_runtime.h>
#include <cstdint>

typedef __attribute__((ext_vector_type(4))) int i32x4;

#define XROWS  22
#define ROWB   2048              // LDS bytes per staged row (w 0..31, 64B each)
#define WSLICE 8192
#define WB_BYTES 409600          // wb (401408) rounded to 4KB
#define XT_BYTES ((size_t)16 * 112 * 128 * 64)

__device__ __forceinline__ void g2lds16(const void* g, void* l) {
  __builtin_amdgcn_global_load_lds(
      (const __attribute__((address_space(1))) unsigned int*)g,
      (__attribute__((address_space(3))) unsigned int*)l, 16, 0, 0);
}

// ---- W pack: wb[((s*4 + g)*128 + co)*16 + lo], ci = g*16+lo, s = kh*7+kw
__global__ void prep_w(const float* __restrict__ w1,
                       const float* __restrict__ w2,
                       const float* __restrict__ w3,
                       signed char* __restrict__ wb) {
  int t = blockIdx.x * 256 + threadIdx.x;
  int lo = t & 15;
  int co = (t >> 4) & 127;
  int g  = (t >> 11) & 3;
  int s  = t >> 13;
  if (s >= 49) return;
  int kh = s / 7, kw = s % 7;
  int ci = g * 16 + lo;
  int base = ((co * 64 + ci) * 7 + kh) * 3;
  float v;
  if (kw < 3)       v = w1[base + kw];
  else if (kw == 3) v = w2[base + 1];
  else              v = w3[base + kw - 4];
  wb[t] = (signed char)(int)v;
}

// ---- X pre-transpose: xt[n][h][w(128)][ci(64)] i8, clamped, 16B-granule-swizzled.
// Granule position p within a w's 64B holds ci-granule (p ^ ((w>>1)&3)).
__global__ void prep_x(const int* __restrict__ x, signed char* __restrict__ xt) {
  __shared__ unsigned char T[64 * 68];
  const int tid = threadIdx.x;
  const int wt = blockIdx.x * 64, h = blockIdx.y, n = blockIdx.z;
  {
    const int wr = tid & 63;
    const int cb = (tid >> 6) * 16;
    int ws = wt + wr; ws = ws < 112 ? ws : 111;
    const int* xp = x + (((size_t)n * 64 + cb) * 112 + h) * 112 + ws;
    #pragma unroll
    for (int g4 = 0; g4 < 4; ++g4) {
      uint32_t v = 0;
      #pragma unroll
      for (int j = 0; j < 4; ++j) {
        int a = xp[(g4 * 4 + j) * 12544];
        a = a < 0 ? 0 : (a > 7 ? 7 : a);
        v |= (uint32_t)a << (8 * j);
      }
      *(uint32_t*)&T[wr * 68 + cb + g4 * 4] = v;
    }
  }
  __syncthreads();
  {
    const int wo = tid >> 2, q = tid & 3;
    const int key = ((wt + wo) >> 1) & 3;
    const int sg = (q ^ key) << 4;
    int4 v;
    v.x = *(const int*)&T[wo * 68 + sg + 0];
    v.y = *(const int*)&T[wo * 68 + sg + 4];
    v.z = *(const int*)&T[wo * 68 + sg + 8];
    v.w = *(const int*)&T[wo * 68 + sg + 12];
    *(int4*)&xt[(((size_t)n * 112 + h) * 128 + wt + wo) * 64 + q * 16] = v;
  }
}

#define MFMA(acc, a, b) acc = __builtin_amdgcn_mfma_i32_16x16x64_i8(a, b, acc, 0, 0, 0)

template<bool XT>
__global__ __launch_bounds__(256, 2)
void conv7(const int* __restrict__ x, const signed char* __restrict__ xt,
           const signed char* __restrict__ wb, float* __restrict__ out) {
  __shared__ __align__(16) unsigned char Xs[XROWS * ROWB];   // 45056 B

  const int tid  = threadIdx.x;
  const int lane = tid & 63;
  const int wid  = tid >> 6;
  const int lrow = lane & 15;
  const int lkg  = lane >> 4;

  // bijective n-chunked XCD swizzle: 784 = 8 * 98; XCD k gets n in {2k, 2k+1}
  const int L  = blockIdx.x + 7 * (blockIdx.y + 7 * blockIdx.z);
  const int Lp = (L & 7) * 98 + (L >> 3);
  const int bx = Lp % 7;
  const int t7 = Lp / 7;
  const int by = t7 % 7;
  const int n  = t7 / 7;
  const int ho_base = by * 16;
  const int wo_base = bx * 16;

  const int co_half = wid >> 1;                    // waves: [2 co][2 spatial]
  const int sp_half = wid & 1;
  const signed char* aB = wb + lkg * 2048 + co_half * 1024 + lrow * 16;

  i32x4 A[4], B[8];
  #pragma unroll
  for (int m = 0; m < 4; ++m) A[m] = *(const i32x4*)(aB + m * 256);  // slice 0

  if constexpr (XT) {
    // ---- staging: 2 KiB per row via global_load_lds (source pre-swizzled)
    for (int r = wid; r < XROWS; r += 4) {
      int h = ho_base + r; h = h < 112 ? h : 111;
      const signed char* src = xt + (((size_t)n * 112 + h) * 128 + wo_base) * 64;
      g2lds16(src + lane * 16, &Xs[r * ROWB]);
      g2lds16(src + 1024 + lane * 16, &Xs[r * ROWB + 1024]);
    }
    asm volatile("s_waitcnt vmcnt(0)" ::: "memory");
  } else {
    // ---- fallback staging straight from NCHW x (R3 scheme, stride ROWB)
    const int w_a  = tid & 15,      cg_a = tid >> 4;
    const int w_b2 = 16 + (tid & 7), cg_b2 = tid >> 3;
    const bool doB = (tid < 128) && ((tid & 7) < 6);
    const int keyA = ((w_a >> 1) & 3) << 2;
    const int keyB = ((w_b2 >> 1) & 3) << 2;
    for (int r = 0; r < XROWS; ++r) {
      int h = ho_base + r; h = h < 112 ? h : 111;
      const int* xr = x + (size_t)n * 64 * 12544 + h * 112;
      {
        int wc = wo_base + w_a; wc = wc < 112 ? wc : 111;
        uint32_t v = 0;
        #pragma unroll
        for (int j = 0; j < 4; ++j) {
          int a = xr[(cg_a * 4 + j) * 12544 + wc];
          a = a < 0 ? 0 : (a > 7 ? 7 : a);
          v |= (uint32_t)a << (8 * j);
        }
        *(uint32_t*)&Xs[r * ROWB + w_a * 64 + ((cg_a ^ keyA) << 2)] = v;
      }
      if (doB) {
        int wc = wo_base + w_b2; wc = wc < 112 ? wc : 111;
        uint32_t v = 0;
        #pragma unroll
        for (int j = 0; j < 4; ++j) {
          int a = xr[(cg_b2 * 4 + j) * 12544 + wc];
          a = a < 0 ? 0 : (a > 7 ? 7 : a);
          v |= (uint32_t)a << (8 * j);
        }
        *(uint32_t*)&Xs[r * ROWB + w_b2 * 64 + ((cg_b2 ^ keyB) << 2)] = v;
      }
    }
  }
  __syncthreads();

  i32x4 acc[4][8];
  #pragma unroll
  for (int m = 0; m < 4; ++m)
    #pragma unroll
    for (int b = 0; b < 8; ++b)
      acc[m][b] = (i32x4){0, 0, 0, 0};

  const int rowB = sp_half * 8;

  for (int kw = 0; kw < 7; ++kw) {
    const int w_l  = lrow + kw;
    const int bcol = w_l * 64 + ((lkg ^ ((w_l >> 1) & 3)) << 4);
    #pragma unroll
    for (int b = 0; b < 8; ++b)
      B[b] = *(const i32x4*)&Xs[(rowB + b) * ROWB + bcol];

    #pragma unroll
    for (int kh = 0; kh < 7; ++kh) {
      // next slice in traversal order (kw-outer, kh-inner)
      const signed char* apn = aB + (size_t)(kh < 6 ? (kh + 1) * 7 + kw : kw + 1) * WSLICE;
      __builtin_amdgcn_s_setprio(1);
      #pragma unroll
      for (int m = 0; m < 3; ++m) {
        #pragma unroll
        for (int b = 0; b < 8; ++b)
          MFMA(acc[m][b], A[m], B[(kh + b) & 7]);
        A[m] = *(const i32x4*)(apn + m * 256);     // staggered in-place reload
      }
      MFMA(acc[3][0], A[3], B[kh & 7]);            // last consumer of ring slot kh&7
      if (kh < 6)
        B[kh & 7] = *(const i32x4*)&Xs[(rowB + kh + 8) * ROWB + bcol];
      #pragma unroll
      for (int b = 1; b < 8; ++b)
        MFMA(acc[3][b], A[3], B[(kh + b) & 7]);
      __builtin_amdgcn_s_setprio(0);
      A[3] = *(const i32x4*)(apn + 3 * 256);
    }
  }

  // ---- epilogue: C/D map col=lane&15 (wo), row=(lane>>4)*4+j (co); i32->f32 exact
  const int wo = wo_base + lrow;
  if (wo < 106) {
    #pragma unroll
    for (int m = 0; m < 4; ++m) {
      const int co = co_half * 64 + m * 16 + lkg * 4;
      #pragma unroll
      for (int b = 0; b < 8; ++b) {
        const int ho = ho_base + rowB + b;
        if (ho < 106) {
          float* op = out + (((size_t)n * 128 + co) * 106 + ho) * 106 + wo;
          #pragma unroll
          for (int j = 0; j < 4; ++j)
            op[(size_t)j * 11236] = (float)acc[m][b][j];
        }
      }
    }
  }
}

extern "C" void kernel_launch(void* const* d_in, const int* in_sizes, int n_in,
                              void* d_out, int out_size, void* d_ws, size_t ws_size,
                              hipStream_t stream) {
  const int*   x  = (const int*)d_in[0];
  const float* w1 = (const float*)d_in[1];
  const float* w2 = (const float*)d_in[2];
  const float* w3 = (const float*)d_in[3];
  float* outp = (float*)d_out;
  signed char* wbp = (signed char*)d_ws;
  signed char* xtp = wbp + WB_BYTES;

  prep_w<<<dim3(1568), dim3(256), 0, stream>>>(w1, w2, w3, wbp);
  if (ws_size >= WB_BYTES + XT_BYTES) {
    prep_x<<<dim3(2, 112, 16), dim3(256), 0, stream>>>(x, xtp);
    conv7<true><<<dim3(7, 7, 16), dim3(256), 0, stream>>>(x, xtp, wbp, outp);
  } else {
    conv7<false><<<dim3(7, 7, 16), dim3(256), 0, stream>>>(x, xtp, wbp, outp);
  }
}

// Round 5
// 84.384 us; speedup vs baseline: 1.8322x; 1.0204x over previous
//
#include <hip/hip_runtime.h>
#include <cstdint>

typedef __attribute__((ext_vector_type(4))) int i32x4;

#define XROWS  22
#define ROWB   2048              // LDS bytes per staged row (w 0..31, 64B each)
#define WSLICE 8192
#define WB_BYTES 409600          // wb (401408) rounded to 4KB
#define XT_BYTES ((size_t)16 * 112 * 128 * 64)

__device__ __forceinline__ void g2lds16(const void* g, void* l) {
  __builtin_amdgcn_global_load_lds(
      (const __attribute__((address_space(1))) unsigned int*)g,
      (__attribute__((address_space(3))) unsigned int*)l, 16, 0, 0);
}

// ---- W pack: wb[((s*4 + g)*128 + co)*16 + lo], ci = g*16+lo, s = kh*7+kw
__global__ void prep_w(const float* __restrict__ w1,
                       const float* __restrict__ w2,
                       const float* __restrict__ w3,
                       signed char* __restrict__ wb) {
  int t = blockIdx.x * 256 + threadIdx.x;
  int lo = t & 15;
  int co = (t >> 4) & 127;
  int g  = (t >> 11) & 3;
  int s  = t >> 13;
  if (s >= 49) return;
  int kh = s / 7, kw = s % 7;
  int ci = g * 16 + lo;
  int base = ((co * 64 + ci) * 7 + kh) * 3;
  float v;
  if (kw < 3)       v = w1[base + kw];
  else if (kw == 3) v = w2[base + 1];
  else              v = w3[base + kw - 4];
  wb[t] = (signed char)(int)v;
}

// ---- X pre-transpose: xt[n][h][w(128)][ci(64)] i8, clamped, 16B-granule-swizzled.
__global__ void prep_x(const int* __restrict__ x, signed char* __restrict__ xt) {
  __shared__ unsigned char T[64 * 68];
  const int tid = threadIdx.x;
  const int wt = blockIdx.x * 64, h = blockIdx.y, n = blockIdx.z;
  {
    const int wr = tid & 63;
    const int cb = (tid >> 6) * 16;
    int ws = wt + wr; ws = ws < 112 ? ws : 111;
    const int* xp = x + (((size_t)n * 64 + cb) * 112 + h) * 112 + ws;
    #pragma unroll
    for (int g4 = 0; g4 < 4; ++g4) {
      uint32_t v = 0;
      #pragma unroll
      for (int j = 0; j < 4; ++j) {
        int a = xp[(g4 * 4 + j) * 12544];
        a = a < 0 ? 0 : (a > 7 ? 7 : a);
        v |= (uint32_t)a << (8 * j);
      }
      *(uint32_t*)&T[wr * 68 + cb + g4 * 4] = v;
    }
  }
  __syncthreads();
  {
    const int wo = tid >> 2, q = tid & 3;
    const int key = ((wt + wo) >> 1) & 3;
    const int sg = (q ^ key) << 4;
    int4 v;
    v.x = *(const int*)&T[wo * 68 + sg + 0];
    v.y = *(const int*)&T[wo * 68 + sg + 4];
    v.z = *(const int*)&T[wo * 68 + sg + 8];
    v.w = *(const int*)&T[wo * 68 + sg + 12];
    *(int4*)&xt[(((size_t)n * 112 + h) * 128 + wt + wo) * 64 + q * 16] = v;
  }
}

#define MFMA(acc, a, b) acc = __builtin_amdgcn_mfma_i32_16x16x64_i8(a, b, acc, 0, 0, 0)

template<bool XT>
__global__ __launch_bounds__(256, 3)
void conv7(const int* __restrict__ x, const signed char* __restrict__ xt,
           const signed char* __restrict__ wb, float* __restrict__ out) {
  __shared__ __align__(16) unsigned char Xs[XROWS * ROWB];   // 45056 B

  const int tid  = threadIdx.x;
  const int lane = tid & 63;
  const int wid  = tid >> 6;               // wave = spatial quarter (4 ho rows)
  const int lrow = lane & 15;
  const int lkg  = lane >> 4;

  // chunked XCD swizzle: 1568 = 8 * 196; XCD k gets logical ids [k*196, (k+1)*196)
  // logical id: coh + 2*(bx + 7*(by + 7*n)) -> co-pair adjacent, 2 images per XCD
  const int L  = blockIdx.x;
  const int Lp = (L & 7) * 196 + (L >> 3);
  const int coh = Lp & 1;
  const int r2  = Lp >> 1;
  const int bx  = r2 % 7;
  const int t7  = r2 / 7;
  const int by  = t7 % 7;
  const int n   = t7 / 7;
  const int ho_base = by * 16;
  const int wo_base = bx * 16;

  const signed char* aB = wb + lkg * 2048 + coh * 1024 + lrow * 16;

  i32x4 A[4];
  #pragma unroll
  for (int m = 0; m < 4; ++m) A[m] = *(const i32x4*)(aB + m * 256);  // slice 0

  if constexpr (XT) {
    for (int r = wid; r < XROWS; r += 4) {
      int h = ho_base + r; h = h < 112 ? h : 111;   // clamped rows feed only masked outputs
      const signed char* src = xt + (((size_t)n * 112 + h) * 128 + wo_base) * 64;
      g2lds16(src + lane * 16, &Xs[r * ROWB]);
      g2lds16(src + 1024 + lane * 16, &Xs[r * ROWB + 1024]);
    }
    asm volatile("s_waitcnt vmcnt(0)" ::: "memory");
  } else {
    const int w_a  = tid & 15,       cg_a  = tid >> 4;
    const int w_b2 = 16 + (tid & 7), cg_b2 = tid >> 3;
    const bool doB = (tid < 128) && ((tid & 7) < 6);
    const int keyA = ((w_a >> 1) & 3) << 2;
    const int keyB = ((w_b2 >> 1) & 3) << 2;
    for (int r = 0; r < XROWS; ++r) {
      int h = ho_base + r; h = h < 112 ? h : 111;
      const int* xr = x + (size_t)n * 64 * 12544 + h * 112;
      {
        int wc = wo_base + w_a; wc = wc < 112 ? wc : 111;
        uint32_t v = 0;
        #pragma unroll
        for (int j = 0; j < 4; ++j) {
          int a = xr[(cg_a * 4 + j) * 12544 + wc];
          a = a < 0 ? 0 : (a > 7 ? 7 : a);
          v |= (uint32_t)a << (8 * j);
        }
        *(uint32_t*)&Xs[r * ROWB + w_a * 64 + ((cg_a ^ keyA) << 2)] = v;
      }
      if (doB) {
        int wc = wo_base + w_b2; wc = wc < 112 ? wc : 111;
        uint32_t v = 0;
        #pragma unroll
        for (int j = 0; j < 4; ++j) {
          int a = xr[(cg_b2 * 4 + j) * 12544 + wc];
          a = a < 0 ? 0 : (a > 7 ? 7 : a);
          v |= (uint32_t)a << (8 * j);
        }
        *(uint32_t*)&Xs[r * ROWB + w_b2 * 64 + ((cg_b2 ^ keyB) << 2)] = v;
      }
    }
  }
  __syncthreads();

  i32x4 acc[4][4];
  #pragma unroll
  for (int m = 0; m < 4; ++m)
    #pragma unroll
    for (int b = 0; b < 4; ++b)
      acc[m][b] = (i32x4){0, 0, 0, 0};

  const int rowB = wid * 4;                 // this wave's 4 ho rows

  for (int kw = 0; kw < 7; ++kw) {
    const int w_l  = lrow + kw;
    const int bcol = w_l * 64 + ((lkg ^ ((w_l >> 1) & 3)) << 4);
    i32x4 B[8];
    #pragma unroll
    for (int b = 0; b < 4; ++b)
      B[b] = *(const i32x4*)&Xs[(rowB + b) * ROWB + bcol];

    #pragma unroll
    for (int kh = 0; kh < 7; ++kh) {
      if (kh < 6)                           // row kh+4 into free slot, consumed next kh
        B[(kh + 4) & 7] = *(const i32x4*)&Xs[(rowB + kh + 4) * ROWB + bcol];
      const signed char* apn = aB + (size_t)(kh < 6 ? (kh + 1) * 7 + kw : kw + 1) * WSLICE;
      __builtin_amdgcn_s_setprio(1);
      #pragma unroll
      for (int m = 0; m < 4; ++m) {
        #pragma unroll
        for (int b = 0; b < 4; ++b)
          MFMA(acc[m][b], A[m], B[(kh + b) & 7]);
        A[m] = *(const i32x4*)(apn + m * 256);   // staggered in-place reload
      }
      __builtin_amdgcn_s_setprio(0);
    }
  }

  // ---- epilogue: C/D map col=lane&15 (wo), row=(lane>>4)*4+j (co); i32->f32 exact
  const int wo = wo_base + lrow;
  if (wo < 106) {
    #pragma unroll
    for (int m = 0; m < 4; ++m) {
      const int co = coh * 64 + m * 16 + lkg * 4;
      #pragma unroll
      for (int b = 0; b < 4; ++b) {
        const int ho = ho_base + rowB + b;
        if (ho < 106) {
          float* op = out + (((size_t)n * 128 + co) * 106 + ho) * 106 + wo;
          #pragma unroll
          for (int j = 0; j < 4; ++j)
            op[(size_t)j * 11236] = (float)acc[m][b][j];
        }
      }
    }
  }
}

extern "C" void kernel_launch(void* const* d_in, const int* in_sizes, int n_in,
                              void* d_out, int out_size, void* d_ws, size_t ws_size,
                              hipStream_t stream) {
  const int*   x  = (const int*)d_in[0];
  const float* w1 = (const float*)d_in[1];
  const float* w2 = (const float*)d_in[2];
  const float* w3 = (const float*)d_in[3];
  float* outp = (float*)d_out;
  signed char* wbp = (signed char*)d_ws;
  signed char* xtp = wbp + WB_BYTES;

  prep_w<<<dim3(1568), dim3(256), 0, stream>>>(w1, w2, w3, wbp);
  if (ws_size >= WB_BYTES + XT_BYTES) {
    prep_x<<<dim3(2, 112, 16), dim3(256), 0, stream>>>(x, xtp);
    conv7<true><<<dim3(1568), dim3(256), 0, stream>>>(x, xtp, wbp, outp);
  } else {
    conv7<false><<<dim3(1568), dim3(256), 0, stream>>>(x, xtp, wbp, outp);
  }
}